// Round 3
// baseline (599.769 us; speedup 1.0000x reference)
//
#include <hip/hip_runtime.h>
#include <hip/hip_bf16.h>
#include <stdint.h>

// Problem constants (from reference)
#define M_DIM 8192              // 4*2048 batch*seq rows
#define N_DIM 4096              // out_features
#define K_DIM 4096              // in_features
#define NOG   4096              // num out groups (out_group=1)
#define NIG   512               // num in groups (in_group=8)

typedef __bf16 bf16;
typedef __attribute__((ext_vector_type(8))) __bf16 bf16x8;   // 4 VGPRs — MFMA A/B frag
typedef __attribute__((ext_vector_type(4))) float f32x4;     // MFMA C/D frag

// ---------------------------------------------------------------------------
// async global->LDS, 16 B per lane. LDS dest is wave-uniform base + lane*16.
__device__ __forceinline__ void gload16(const void* g, void* lds) {
    __builtin_amdgcn_global_load_lds(
        (__attribute__((address_space(1))) void*)g,
        (__attribute__((address_space(3))) void*)lds,
        16 /*size*/, 0 /*offset*/, 0 /*aux*/);
}

// ---------------------------------------------------------------------------
// Kernel 1: fp32 -> bf16 convert. 32 B loads / 16 B store per lane.
__global__ __launch_bounds__(256) void k_convert(const float* __restrict__ in,
                                                 bf16* __restrict__ out) {
    int i = blockIdx.x * blockDim.x + threadIdx.x;   // grid sized exactly
    const float4* p = (const float4*)in + (size_t)i * 2;
    float4 a = p[0], b = p[1];
    bf16x8 o;
    o[0] = (bf16)a.x; o[1] = (bf16)a.y; o[2] = (bf16)a.z; o[3] = (bf16)a.w;
    o[4] = (bf16)b.x; o[5] = (bf16)b.y; o[6] = (bf16)b.z; o[7] = (bf16)b.w;
    ((bf16x8*)out)[i] = o;
}

// ---------------------------------------------------------------------------
// Kernel 2: AQLM dequant. One thread per (out_feature o, in_group g):
//   W[o, g*8 .. g*8+7] = codebooks[codes[o,g]] * scales[o]   -> bf16
__global__ __launch_bounds__(256) void k_dequant(const int* __restrict__ codes,
                                                 const float* __restrict__ cb,
                                                 const float* __restrict__ scales,
                                                 bf16* __restrict__ w) {
    int i = blockIdx.x * blockDim.x + threadIdx.x;   // i = o*NIG + g, exact grid
    int o = i >> 9;                                   // NIG = 512
    unsigned code = (unsigned)codes[i];
    float s = scales[o];
    const float4* e = (const float4*)(cb + (size_t)code * 8);
    float4 e0 = e[0], e1 = e[1];
    bf16x8 v;
    v[0] = (bf16)(e0.x * s); v[1] = (bf16)(e0.y * s);
    v[2] = (bf16)(e0.z * s); v[3] = (bf16)(e0.w * s);
    v[4] = (bf16)(e1.x * s); v[5] = (bf16)(e1.y * s);
    v[6] = (bf16)(e1.z * s); v[7] = (bf16)(e1.w * s);
    ((bf16x8*)w)[i] = v;
}

// ---------------------------------------------------------------------------
// Kernel 3: C[m,n] = sum_k A[m,k]*B[n,k] + bias[n]   (NT gemm, B = dequant W)
// BM=256 x BN=128 x BK=64, 4 waves (2x2), wave tile 128x64.
//
// LDS is stored in FRAGMENT-READ order, not row-major: for each 16-row group
// g and K-half h (32 cols), the 64 16-B chunks are ordered [kblk][row], so a
// wave's ds_read_b128 of one fragment touches 1024 CONSECUTIVE bytes ->
// zero bank conflicts by construction. global_load_lds's fixed lane->LDS
// mapping (base + lane*16) realizes this by choosing each lane's GLOBAL
// source: lane l fetches (row = l&15, kblk = l>>4) of its group.
#define BM 256
#define BN 128
#define BK 64
#define KSTEPS (K_DIM / BK)

__global__ __launch_bounds__(256, 2) void k_gemm_bt_bias(
    const bf16* __restrict__ A,      // [M_DIM, K_DIM]
    const bf16* __restrict__ B,      // [N_DIM, K_DIM]
    const float* __restrict__ bias,  // [N_DIM]
    float* __restrict__ C)           // [M_DIM, N_DIM]
{
    // Chunk-permuted layout: group g (16 rows), half h (32 cols):
    //   elem offset = ((g*2 + h)*64 + kblk*16 + row) * 8
    __shared__ __align__(16) bf16 As[BM * BK];   // 32 KB, 16 groups x 2 halves
    __shared__ __align__(16) bf16 Bs[BN * BK];   // 16 KB,  8 groups x 2 halves

    const int tid  = threadIdx.x;
    const int wave = tid >> 6;         // 0..3
    const int lane = tid & 63;
    const int quad = lane >> 4;        // 0..3
    const int l16  = lane & 15;

    const int bm0 = blockIdx.y * BM;
    const int bn0 = blockIdx.x * BN;

    const int wm = (wave >> 1) * 128;  // wave's 128x64 subtile
    const int wn = (wave & 1) * 64;

    // Staging source for lane l: row l&15 of the group, 16-B block l>>4.
    const int srow = lane & 15;
    const int skb  = lane >> 4;

    // A: wave stages groups 4w..4w+3 (rows w*64..w*64+64), halves h=0,1.
    // B: wave stages groups 2w..2w+1 (rows w*32..w*32+32), halves h=0,1.
    const bf16* Ag = A + (size_t)(bm0 + wave * 64 + srow) * K_DIM + skb * 8;
    const bf16* Bg = B + (size_t)(bn0 + wave * 32 + srow) * K_DIM + skb * 8;
    bf16* AsW = As + (size_t)(wave * 4 * 2) * 512;   // group 4w, h=0 chunk base
    bf16* BsW = Bs + (size_t)(wave * 2 * 2) * 512;   // group 2w, h=0

    const size_t rstep = (size_t)16 * K_DIM;         // one group of rows

    const int gA0 = wm >> 4;           // first A group this wave reads
    const int gB0 = wn >> 4;           // first B group this wave reads

    f32x4 acc[8][4] = {};

    for (int ks = 0; ks < KSTEPS; ++ks) {
        #pragma unroll
        for (int gi = 0; gi < 4; ++gi) {
            gload16(Ag + gi * rstep,      AsW + (gi * 2 + 0) * 512);
            gload16(Ag + gi * rstep + 32, AsW + (gi * 2 + 1) * 512);
        }
        #pragma unroll
        for (int gi = 0; gi < 2; ++gi) {
            gload16(Bg + gi * rstep,      BsW + (gi * 2 + 0) * 512);
            gload16(Bg + gi * rstep + 32, BsW + (gi * 2 + 1) * 512);
        }
        Ag += BK; Bg += BK;
        __syncthreads();   // drains vmcnt -> staged data visible

        // Fragment reads: position within group = quad*16 + l16 = lane ->
        // 64 consecutive chunks, conflict-free.
        bf16x8 af0[8], af1[8], bf0[4], bf1[4];
        #pragma unroll
        for (int t = 0; t < 8; ++t) {
            af0[t] = *(const bf16x8*)(As + ((size_t)((gA0 + t) * 2 + 0) * 64 + lane) * 8);
            af1[t] = *(const bf16x8*)(As + ((size_t)((gA0 + t) * 2 + 1) * 64 + lane) * 8);
        }
        #pragma unroll
        for (int t = 0; t < 4; ++t) {
            bf0[t] = *(const bf16x8*)(Bs + ((size_t)((gB0 + t) * 2 + 0) * 64 + lane) * 8);
            bf1[t] = *(const bf16x8*)(Bs + ((size_t)((gB0 + t) * 2 + 1) * 64 + lane) * 8);
        }

        #pragma unroll
        for (int i = 0; i < 8; ++i)
            #pragma unroll
            for (int j = 0; j < 4; ++j)
                acc[i][j] = __builtin_amdgcn_mfma_f32_16x16x32_bf16(
                    af0[i], bf0[j], acc[i][j], 0, 0, 0);
        #pragma unroll
        for (int i = 0; i < 8; ++i)
            #pragma unroll
            for (int j = 0; j < 4; ++j)
                acc[i][j] = __builtin_amdgcn_mfma_f32_16x16x32_bf16(
                    af1[i], bf1[j], acc[i][j], 0, 0, 0);

        __syncthreads();   // all reads done before next overwrite
    }

    // Epilogue: C/D layout col = lane&15, row = quad*4 + reg  [m89/m91-verified]
    #pragma unroll
    for (int j = 0; j < 4; ++j) {
        const int gn = bn0 + wn + j * 16 + l16;
        const float bz = bias[gn];
        #pragma unroll
        for (int i = 0; i < 8; ++i) {
            float* cp = C + (size_t)(bm0 + wm + i * 16 + quad * 4) * N_DIM + gn;
            #pragma unroll
            for (int r = 0; r < 4; ++r)
                cp[(size_t)r * N_DIM] = acc[i][j][r] + bz;
        }
    }
}

// ---------------------------------------------------------------------------
extern "C" void kernel_launch(void* const* d_in, const int* in_sizes, int n_in,
                              void* d_out, int out_size, void* d_ws, size_t ws_size,
                              hipStream_t stream) {
    const float* input     = (const float*)d_in[0];   // [4,2048,4096]
    const int*   codes     = (const int*)d_in[1];     // [4096,512,1]
    const float* codebooks = (const float*)d_in[2];   // [1,65536,1,8]
    const float* scales    = (const float*)d_in[3];   // [4096]
    const float* bias      = (const float*)d_in[4];   // [4096]
    float* out = (float*)d_out;                        // [4,2048,4096]

    // Workspace: A_bf16 (67.1 MB) then W_bf16 (33.5 MB); both fully written
    // before the GEMM reads them, so the 0xAA poison is irrelevant.
    bf16* Abf = (bf16*)d_ws;
    bf16* Wbf = (bf16*)((char*)d_ws + (size_t)M_DIM * K_DIM * sizeof(bf16));

    (void)in_sizes; (void)n_in; (void)out_size; (void)ws_size;

    // 1) activation fp32 -> bf16  (8 elems/thread, exact grid)
    k_convert<<<(M_DIM * (size_t)K_DIM / 8) / 256, 256, 0, stream>>>(input, Abf);

    // 2) dequantize W -> bf16  (one thread per (o, g), exact grid)
    k_dequant<<<((size_t)NOG * NIG) / 256, 256, 0, stream>>>(codes, codebooks, scales, Wbf);

    // 3) NT GEMM + bias
    dim3 grid(N_DIM / BN, M_DIM / BM);   // (32, 32)
    k_gemm_bt_bias<<<grid, 256, 0, stream>>>(Abf, Wbf, bias, out);
}

// Round 4
// 471.879 us; speedup vs baseline: 1.2710x; 1.2710x over previous
//
#include <hip/hip_runtime.h>
#include <hip/hip_bf16.h>
#include <stdint.h>

// Problem constants (from reference)
#define M_DIM 8192              // 4*2048 batch*seq rows
#define N_DIM 4096              // out_features
#define K_DIM 4096              // in_features
#define NOG   4096              // num out groups (out_group=1)
#define NIG   512               // num in groups (in_group=8)

typedef __bf16 bf16;
typedef __attribute__((ext_vector_type(8))) __bf16 bf16x8;   // 4 VGPRs — MFMA A/B frag
typedef __attribute__((ext_vector_type(4))) float f32x4;     // MFMA C/D frag

// Tiled bf16 layout for both GEMM operands ("chunk order"):
//   tile(g, h) = rows [g*16,(g+1)*16) x cols [h*32,(h+1)*32)
//   stored as 64 consecutive 16-B chunks, chunk index c = kblk*16 + row
//   (kblk = 8-elem block within the 32 cols, row = row within group).
//   tile base (in chunks) = (g * (K_DIM/32) + h) * 64.
// GEMM staging then reads 1024 CONTIGUOUS bytes per gload16 (lane l -> chunk l)
// and LDS receives fragment-read order -> zero bank conflicts.

// ---------------------------------------------------------------------------
// async global->LDS, 16 B per lane. LDS dest is wave-uniform base + lane*16.
__device__ __forceinline__ void gload16(const void* g, void* lds) {
    __builtin_amdgcn_global_load_lds(
        (__attribute__((address_space(1))) void*)g,
        (__attribute__((address_space(3))) void*)lds,
        16 /*size*/, 0 /*offset*/, 0 /*aux*/);
}

// ---------------------------------------------------------------------------
// Kernel 1: fp32 -> bf16 convert + transpose into chunk-order tiles.
// Block = 256 threads handles 16 rows x 128 cols (4 tiles). Coalesced fp32
// reads; LDS (4 KB) does the chunk permutation; coalesced 16-B chunk stores.
__global__ __launch_bounds__(256) void k_convert_tile(const float* __restrict__ in,
                                                      bf16* __restrict__ out) {
    __shared__ __align__(16) bf16 tile[256 * 8];   // 4 KB = 256 chunks
    const int t   = threadIdx.x;
    const int g   = blockIdx.y;          // row group (16 rows)
    const int h0  = blockIdx.x * 4;      // first 32-col half of the 4 we cover
    const int row = t >> 4;
    const int cc  = t & 15;              // 8-elem column chunk within 128 cols
    const float4* p = (const float4*)(in + (size_t)(g * 16 + row) * K_DIM
                                         + h0 * 32 + cc * 8);
    float4 a = p[0], b = p[1];
    bf16x8 v;
    v[0] = (bf16)a.x; v[1] = (bf16)a.y; v[2] = (bf16)a.z; v[3] = (bf16)a.w;
    v[4] = (bf16)b.x; v[5] = (bf16)b.y; v[6] = (bf16)b.z; v[7] = (bf16)b.w;
    // chunk-order position within the block's 4 tiles:
    const int widx = (cc >> 2) * 64 + (cc & 3) * 16 + row;
    ((bf16x8*)tile)[widx] = v;
    __syncthreads();
    bf16x8 o = ((bf16x8*)tile)[t];
    ((bf16x8*)out)[((size_t)g * 128 + h0) * 64 + t] = o;   // contiguous 4 KB store
}

// ---------------------------------------------------------------------------
// Kernel 2: AQLM dequant straight into chunk-order tiles. Block = 256 threads
// handles one 16-row out-group span x 16 in-groups (4 tiles); thread t's
// output chunk index within the block is exactly t -> coalesced stores.
__global__ __launch_bounds__(256) void k_dequant_tile(const int* __restrict__ codes,
                                                      const float* __restrict__ cb,
                                                      const float* __restrict__ scales,
                                                      bf16* __restrict__ w) {
    const int t    = threadIdx.x;
    const int gB   = blockIdx.y;           // out-feature group (16 rows)
    const int h0   = blockIdx.x * 4;       // first 32-col half
    const int hl   = t >> 6;               // half within block (0..3)
    const int kblk = (t >> 4) & 3;         // in-group within half
    const int row  = t & 15;               // out-feature within group
    const int o    = gB * 16 + row;
    const int iG   = blockIdx.x * 16 + hl * 4 + kblk;
    unsigned code = (unsigned)codes[o * NIG + iG];
    float s = scales[o];
    const float4* e = (const float4*)(cb + (size_t)code * 8);
    float4 e0 = e[0], e1 = e[1];
    bf16x8 v;
    v[0] = (bf16)(e0.x * s); v[1] = (bf16)(e0.y * s);
    v[2] = (bf16)(e0.z * s); v[3] = (bf16)(e0.w * s);
    v[4] = (bf16)(e1.x * s); v[5] = (bf16)(e1.y * s);
    v[6] = (bf16)(e1.z * s); v[7] = (bf16)(e1.w * s);
    ((bf16x8*)w)[((size_t)gB * 128 + h0) * 64 + t] = v;
}

// ---------------------------------------------------------------------------
// Kernel 3: C[m,n] = sum_k A[m,k]*B[n,k] + bias[n]  on chunk-order tiles.
// BM=256 x BN=128 x BK=64, 4 waves (2x2), wave tile 128x64.
// Staging: each gload16 reads 1024 contiguous global bytes -> LDS in fragment
// order. Fragment ds_read_b128: 64 consecutive chunks -> conflict-free.
#define BM 256
#define BN 128
#define BK 64
#define KSTEPS (K_DIM / BK)

__global__ __launch_bounds__(256, 2) void k_gemm_tiled(
    const bf16* __restrict__ A,      // chunk-order tiled [512 groups][128 halves]
    const bf16* __restrict__ B,      // chunk-order tiled [256 groups][128 halves]
    const float* __restrict__ bias,  // [N_DIM]
    float* __restrict__ C)           // [M_DIM, N_DIM] row-major
{
    // LDS: per group-half 512 elems (64 chunks); As = 16 groups x 2 halves.
    __shared__ __align__(16) bf16 As[BM * BK];   // 32 KB
    __shared__ __align__(16) bf16 Bs[BN * BK];   // 16 KB

    const int tid  = threadIdx.x;
    const int wave = tid >> 6;         // 0..3
    const int lane = tid & 63;
    const int quad = lane >> 4;        // 0..3
    const int l16  = lane & 15;

    const int bn0 = blockIdx.x * BN;
    const int bm0 = blockIdx.y * BM;
    const int wm = (wave >> 1) * 128;  // wave's 128x64 subtile
    const int wn = (wave & 1) * 64;

    // Staging sources: lane l fetches chunk l of each group-half tile.
    // Group stride in chunks = 128 halves * 64 = 8192; elems = *8.
    const bf16* pA[4];
    const bf16* pB[2];
    #pragma unroll
    for (int gi = 0; gi < 4; ++gi) {
        const int g = blockIdx.y * 16 + wave * 4 + gi;     // A group
        pA[gi] = A + ((size_t)g * 8192 + lane) * 8;
    }
    #pragma unroll
    for (int gi = 0; gi < 2; ++gi) {
        const int g = blockIdx.x * 8 + wave * 2 + gi;      // B group
        pB[gi] = B + ((size_t)g * 8192 + lane) * 8;
    }
    bf16* AsW = As + wave * 4096;      // wave's 4 A-groups (4*2*512)
    bf16* BsW = Bs + wave * 2048;      // wave's 2 B-groups

    const int gA0 = (wave >> 1) * 8;   // first A group this wave reads
    const int gB0 = (wave & 1) * 4;    // first B group this wave reads

    f32x4 acc[8][4] = {};

    for (int ks = 0; ks < KSTEPS; ++ks) {
        #pragma unroll
        for (int gi = 0; gi < 4; ++gi) {
            gload16(pA[gi],       AsW + gi * 1024);        // half 0: 1024 B contig
            gload16(pA[gi] + 512, AsW + gi * 1024 + 512);  // half 1
            pA[gi] += 1024;                                 // advance 2 halves
        }
        #pragma unroll
        for (int gi = 0; gi < 2; ++gi) {
            gload16(pB[gi],       BsW + gi * 1024);
            gload16(pB[gi] + 512, BsW + gi * 1024 + 512);
            pB[gi] += 1024;
        }
        __syncthreads();   // drains vmcnt -> staged data visible

        // Fragment reads: 64 consecutive chunks per read -> conflict-free.
        // Lane's elems: A[m = l16][k = quad*8..+8] of (group, half).
        bf16x8 af0[8], af1[8], bq0[4], bq1[4];
        #pragma unroll
        for (int t = 0; t < 8; ++t) {
            af0[t] = *(const bf16x8*)(As + (size_t)(gA0 + t) * 1024 + lane * 8);
            af1[t] = *(const bf16x8*)(As + (size_t)(gA0 + t) * 1024 + 512 + lane * 8);
        }
        #pragma unroll
        for (int t = 0; t < 4; ++t) {
            bq0[t] = *(const bf16x8*)(Bs + (size_t)(gB0 + t) * 1024 + lane * 8);
            bq1[t] = *(const bf16x8*)(Bs + (size_t)(gB0 + t) * 1024 + 512 + lane * 8);
        }

        #pragma unroll
        for (int i = 0; i < 8; ++i)
            #pragma unroll
            for (int j = 0; j < 4; ++j)
                acc[i][j] = __builtin_amdgcn_mfma_f32_16x16x32_bf16(
                    af0[i], bq0[j], acc[i][j], 0, 0, 0);
        #pragma unroll
        for (int i = 0; i < 8; ++i)
            #pragma unroll
            for (int j = 0; j < 4; ++j)
                acc[i][j] = __builtin_amdgcn_mfma_f32_16x16x32_bf16(
                    af1[i], bq1[j], acc[i][j], 0, 0, 0);

        __syncthreads();   // all reads done before next overwrite
    }

    // Epilogue: C/D layout col = lane&15, row = quad*4 + reg  [m89/m91-verified]
    #pragma unroll
    for (int j = 0; j < 4; ++j) {
        const int gn = bn0 + wn + j * 16 + l16;
        const float bz = bias[gn];
        #pragma unroll
        for (int i = 0; i < 8; ++i) {
            float* cp = C + (size_t)(bm0 + wm + i * 16 + quad * 4) * N_DIM + gn;
            #pragma unroll
            for (int r = 0; r < 4; ++r)
                cp[(size_t)r * N_DIM] = acc[i][j][r] + bz;
        }
    }
}

// ---------------------------------------------------------------------------
extern "C" void kernel_launch(void* const* d_in, const int* in_sizes, int n_in,
                              void* d_out, int out_size, void* d_ws, size_t ws_size,
                              hipStream_t stream) {
    const float* input     = (const float*)d_in[0];   // [4,2048,4096]
    const int*   codes     = (const int*)d_in[1];     // [4096,512,1]
    const float* codebooks = (const float*)d_in[2];   // [1,65536,1,8]
    const float* scales    = (const float*)d_in[3];   // [4096]
    const float* bias      = (const float*)d_in[4];   // [4096]
    float* out = (float*)d_out;                        // [4,2048,4096]

    // Workspace: A_tiled (67.1 MB) then W_tiled (33.5 MB); both fully written
    // before the GEMM reads them, so the 0xAA poison is irrelevant.
    bf16* Abf = (bf16*)d_ws;
    bf16* Wbf = (bf16*)((char*)d_ws + (size_t)M_DIM * K_DIM * sizeof(bf16));

    (void)in_sizes; (void)n_in; (void)out_size; (void)ws_size;

    // 1) activation fp32 -> bf16, tiled  (grid: 32 col-quads x 512 row-groups)
    {
        dim3 g(K_DIM / 128, M_DIM / 16);
        k_convert_tile<<<g, 256, 0, stream>>>(input, Abf);
    }
    // 2) dequantize W -> bf16, tiled  (grid: 32 col-quads x 256 row-groups)
    {
        dim3 g(K_DIM / 128, NOG / 16);
        k_dequant_tile<<<g, 256, 0, stream>>>(codes, codebooks, scales, Wbf);
    }
    // 3) NT GEMM + bias on tiled operands
    {
        dim3 g(N_DIM / BN, M_DIM / BM);   // (32, 32)
        k_gemm_tiled<<<g, 256, 0, stream>>>(Abf, Wbf, bias, out);
    }
}